// Round 6
// baseline (306.489 us; speedup 1.0000x reference)
//
#include <hip/hip_runtime.h>

// B=8, C=64, D=8 (q/k), H=W=128.  dwconv3x3 -> CCA -> CCA -> pointwise.
// Round 5: ccdir split into proj (q,k,v GEMM, both orients) + attn
// (E/softmax/O only) to cut per-wave registers (~200 -> ~110) and the
// barrier chain (7 -> 3).  q,k stored [b][r][p][8] (direct coalesced stores
// from C-frags), v stored [b][r][d][c].  All intermediates bf16.
// Fragment layouts (mfma_f32_16x16x32_bf16):
//   A[m=lane&15][k=quad*8+j (+32s)], B[k][n=lane&15], C col=lane&15,row=quad*4+reg

#define NEGINF -3.0e38f

typedef __attribute__((ext_vector_type(8))) __bf16 bf8;
typedef __attribute__((ext_vector_type(4))) float f4;

__device__ __forceinline__ f4 MFMA(bf8 a, bf8 b, f4 c) {
  return __builtin_amdgcn_mfma_f32_16x16x32_bf16(a, b, c, 0, 0, 0);
}
__device__ __forceinline__ ushort bfb(float f) {
  __bf16 h = (__bf16)f;
  return *(ushort*)&h;
}

// 32x32-tile dwconv3x3; writes y and yT (bf16), packed ushort2 stores.
__global__ __launch_bounds__(256) void dwconv_kernel(
    const float* __restrict__ x, const float* __restrict__ wdw,
    __bf16* __restrict__ y, __bf16* __restrict__ yT) {
  __shared__ float in[34][36];
  __shared__ float ot[32][33];
  int tx = threadIdx.x & 31, ty = threadIdx.x >> 5;   // 32x8
  int w0 = blockIdx.x*32, h0 = blockIdx.y*32;
  int n = blockIdx.z;                                  // b*64 + c
  const float* xp = x + (size_t)n*16384;
  const float* wp = wdw + (n & 63)*9;
  float wr[9];
  #pragma unroll
  for (int j = 0; j < 9; ++j) wr[j] = wp[j];
  for (int i = ty; i < 34; i += 8) {
    int hh = h0 + i - 1;
    for (int j = tx; j < 34; j += 32) {
      int ww = w0 + j - 1;
      float v = 0.f;
      if (hh >= 0 && hh < 128 && ww >= 0 && ww < 128) v = xp[hh*128 + ww];
      in[i][j] = v;
    }
  }
  __syncthreads();
  for (int i2 = ty; i2 < 32; i2 += 8) {
    float acc = 0.f;
    #pragma unroll
    for (int kh = 0; kh < 3; ++kh)
      #pragma unroll
      for (int kw = 0; kw < 3; ++kw)
        acc += wr[kh*3 + kw]*in[i2 + kh][tx + kw];
    ot[i2][tx] = acc;
  }
  __syncthreads();
  ushort* yp  = (ushort*)(y  + (size_t)n*16384);
  ushort* ytp = (ushort*)(yT + (size_t)n*16384);
  for (int idx = threadIdx.x; idx < 512; idx += 256) {
    int row = idx >> 4, c2 = (idx & 15)*2;
    ushort2 u;
    u.x = bfb(ot[row][c2]); u.y = bfb(ot[row][c2 + 1]);
    *(ushort2*)&yp[(size_t)(h0 + row)*128 + w0 + c2] = u;
    ushort2 v;
    v.x = bfb(ot[c2][row]); v.y = bfb(ot[c2 + 1][row]);
    *(ushort2*)&ytp[(size_t)(w0 + row)*128 + h0 + c2] = v;
  }
}

// Projection: per (r,b,orient) slice, compute q,k -> [b][r][p][8] (direct
// coalesced stores from C-frags) and v -> [b][r][d][c] (LDS restage).
__global__ __launch_bounds__(256) void proj_kernel(
    const __bf16* __restrict__ srcRow, const __bf16* __restrict__ srcCol,
    const float* __restrict__ wq, const float* __restrict__ wk,
    const float* __restrict__ wv,
    __bf16* __restrict__ qR, __bf16* __restrict__ kR, __bf16* __restrict__ vR,
    __bf16* __restrict__ qT, __bf16* __restrict__ kT, __bf16* __restrict__ vT) {
  // LDS: ys[128][64]b swizzled @0 (16384); after barrier, per-wave v-stage
  // [64][34]b @4352*w (17408).  Total 17408.
  __shared__ __align__(16) char smem[17408];
  __bf16* ys = (__bf16*)smem;
  int t = threadIdx.x;
  int r = blockIdx.x, b = blockIdx.y, orient = blockIdx.z;
  const __bf16* src = orient ? srcCol : srcRow;
  __bf16* qO = orient ? qT : qR;
  __bf16* kO = orient ? kT : kR;
  __bf16* vO = orient ? vT : vR;
  size_t sidx = (size_t)b*128 + r;
  const ushort* sp = (const ushort*)(src + (size_t)b*1048576 + (size_t)r*128);

  for (int i = t; i < 4096; i += 256) {
    int p = i & 127, c = (i >> 7)*2;
    ushort u0 = sp[(size_t)c*16384 + p];
    ushort u1 = sp[(size_t)(c + 1)*16384 + p];
    int cs = c ^ ((p & 7) << 3);
    ushort2 uv; uv.x = u0; uv.y = u1;
    *(ushort2*)((ushort*)ys + p*64 + cs) = uv;
  }
  int lane = t & 63, w = t >> 6;
  int l16 = lane & 15, quad = lane >> 4;

  bf8 a_qk[2], a_wv[4][2];
  {
    const float* wr = (l16 < 8) ? (wq + l16*64) : (wk + (l16 - 8)*64);
    #pragma unroll
    for (int s = 0; s < 2; ++s) {
      int c0 = quad*8 + s*32;
      bf8 f;
      #pragma unroll
      for (int j = 0; j < 8; ++j) f[j] = (__bf16)wr[c0 + j];
      a_qk[s] = f;
    }
    #pragma unroll
    for (int m0 = 0; m0 < 4; ++m0) {
      const float* vr = wv + (m0*16 + l16)*64;
      #pragma unroll
      for (int s = 0; s < 2; ++s) {
        int c0 = quad*8 + s*32;
        bf8 f;
        #pragma unroll
        for (int j = 0; j < 8; ++j) f[j] = (__bf16)vr[c0 + j];
        a_wv[m0][s] = f;
      }
    }
  }
  __syncthreads();                      // ys staged

  f4 z4 = {0.f, 0.f, 0.f, 0.f};
  bf8 b_ys[2][2];
  #pragma unroll
  for (int nt = 0; nt < 2; ++nt) {
    int p = w*32 + nt*16 + l16;
    #pragma unroll
    for (int s = 0; s < 2; ++s)
      b_ys[nt][s] = *(const bf8*)&ys[p*64 + ((s*32 + quad*8) ^ ((p & 7) << 3))];
  }
  // q,k: direct coalesced global stores (per nt: 16 p x 16B contiguous per buf)
  #pragma unroll
  for (int nt = 0; nt < 2; ++nt) {
    int p = w*32 + nt*16 + l16;
    f4 aqk = z4;
    aqk = MFMA(a_qk[0], b_ys[nt][0], aqk);
    aqk = MFMA(a_qk[1], b_ys[nt][1], aqk);
    ushort4 u;
    u.x = bfb(aqk[0]); u.y = bfb(aqk[1]); u.z = bfb(aqk[2]); u.w = bfb(aqk[3]);
    ushort* dq = (ushort*)(((quad < 2) ? qO : kO) + (sidx*128 + p)*8 + (quad & 1)*4);
    *(ushort4*)dq = u;
  }
  // v
  f4 vacc[4][2];
  #pragma unroll
  for (int m0 = 0; m0 < 4; ++m0)
    #pragma unroll
    for (int nt = 0; nt < 2; ++nt) {
      f4 va = z4;
      va = MFMA(a_wv[m0][0], b_ys[nt][0], va);
      va = MFMA(a_wv[m0][1], b_ys[nt][1], va);
      vacc[m0][nt] = va;
    }
  __syncthreads();                      // all ys reads done; reuse as v-stage
  __bf16* vstage = (__bf16*)(smem + 4352*w);   // [64][34] per wave
  #pragma unroll
  for (int m0 = 0; m0 < 4; ++m0)
    #pragma unroll
    for (int nt = 0; nt < 2; ++nt)
      #pragma unroll
      for (int rg = 0; rg < 4; ++rg)
        vstage[(m0*16 + quad*4 + rg)*34 + nt*16 + l16] = (__bf16)vacc[m0][nt][rg];
  // own-wave region only: no barrier needed
  ushort* vp = (ushort*)(vO + (sidx*64)*128 + w*32);
  ushort* vsu = (ushort*)vstage;
  for (int i = lane; i < 1024; i += 64) {
    int d = i >> 4, c2 = (i & 15)*2;
    *(ushort2*)&vp[(size_t)d*128 + c2] = *(ushort2*)&vsu[d*34 + c2];
  }
}

// Attention: per (r,b,dir) slice.  Stage q,k,v (contiguous copies), E via
// MFMA (K=8 in quad0), per-row stats (m,s -> global, normalization deferred),
// P=exp(e-m) bf16 -> LDS, O = V x P^T, store unnormalized O.
__global__ __launch_bounds__(256) void attn_kernel(
    const __bf16* __restrict__ qRb, const __bf16* __restrict__ kRb,
    const __bf16* __restrict__ vRb,
    const __bf16* __restrict__ qTb, const __bf16* __restrict__ kTb,
    const __bf16* __restrict__ vTb,
    __bf16* __restrict__ dstRow, __bf16* __restrict__ dstCol,
    float* __restrict__ mW, float* __restrict__ sW,
    float* __restrict__ mH, float* __restrict__ sH) {
  // LDS: vs[64][136]b @0 (17408); qs[128][8]b @17408; ks @19456;
  // ps[128][72]b @21504 (18432; per-wave out-stage [64][34]b aliases it).
  __shared__ __align__(16) char smem[39936];
  __bf16* vs = (__bf16*)smem;
  __bf16* qs = (__bf16*)(smem + 17408);
  __bf16* ks = (__bf16*)(smem + 19456);
  __bf16* ps = (__bf16*)(smem + 21504);

  int t = threadIdx.x;
  int r = blockIdx.x, b = blockIdx.y, dir = blockIdx.z;
  const __bf16* qb = dir ? qTb : qRb;
  const __bf16* kb = dir ? kTb : kRb;
  const __bf16* vb = dir ? vTb : vRb;
  __bf16* dst      = dir ? dstCol : dstRow;
  float* mo        = dir ? mH : mW;
  float* so        = dir ? sH : sW;
  size_t sidx = (size_t)b*128 + r;

  // stage q,k (2 KB each, one ushort4 per thread) and v (16 KB, pad 136)
  ((ushort4*)qs)[t] = ((const ushort4*)(qb + sidx*1024))[t];
  ((ushort4*)ks)[t] = ((const ushort4*)(kb + sidx*1024))[t];
  const ushort* vp = (const ushort*)(vb + sidx*8192);
  for (int i = t; i < 4096; i += 256) {
    int d = i >> 6, c2 = (i & 63)*2;
    *(ushort2*)((ushort*)vs + d*136 + c2) = *(const ushort2*)&vp[d*128 + c2];
  }
  int lane = t & 63, w = t >> 6;
  int l16 = lane & 15, quad = lane >> 4;
  __syncthreads();                      // staging visible

  f4 z4 = {0.f, 0.f, 0.f, 0.f};
  bf8 zb;
  #pragma unroll
  for (int j = 0; j < 8; ++j) zb[j] = (__bf16)0.f;

  int sb = (int)sidx << 7;
  #pragma unroll
  for (int mt = 0; mt < 2; ++mt) {
    int p = w*32 + mt*16 + l16;
    bf8 aq = (quad == 0) ? *(const bf8*)&qs[p*8] : zb;
    f4 e[8];
    #pragma unroll
    for (int nt = 0; nt < 8; ++nt) {
      bf8 bk = (quad == 0) ? *(const bf8*)&ks[(nt*16 + l16)*8] : zb;
      e[nt] = MFMA(aq, bk, z4);
    }
    if (dir) {                          // diag mask: c == p
      #pragma unroll
      for (int nt = 0; nt < 8; ++nt)
        #pragma unroll
        for (int rg = 0; rg < 4; ++rg)
          if (nt == 2*w + mt && l16 == quad*4 + rg) e[nt][rg] = NEGINF;
    }
    float mx[4], sm[4];
    #pragma unroll
    for (int rg = 0; rg < 4; ++rg) {
      float m2 = e[0][rg];
      #pragma unroll
      for (int nt = 1; nt < 8; ++nt) m2 = fmaxf(m2, e[nt][rg]);
      #pragma unroll
      for (int d2 = 1; d2 < 16; d2 <<= 1) m2 = fmaxf(m2, __shfl_xor(m2, d2, 64));
      mx[rg] = m2;
      sm[rg] = 0.f;
    }
    int prow = w*32 + mt*16 + quad*4;
    #pragma unroll
    for (int nt = 0; nt < 8; ++nt)
      #pragma unroll
      for (int rg = 0; rg < 4; ++rg) {
        float pv = __expf(e[nt][rg] - mx[rg]);
        sm[rg] += pv;
        ps[(prow + rg)*72 + nt*16 + l16] = (__bf16)pv;
      }
    #pragma unroll
    for (int rg = 0; rg < 4; ++rg) {
      float s2 = sm[rg];
      #pragma unroll
      for (int d2 = 1; d2 < 16; d2 <<= 1) s2 += __shfl_xor(s2, d2, 64);
      if (l16 == 0) {
        mo[sb + prow + rg] = mx[rg];
        so[sb + prow + rg] = s2;
      }
    }
  }
  __syncthreads();                      // ps visible

  // O = V x P^T  (M=64 d, N=32 p per wave, K=128)
  f4 acc[4][2];
  #pragma unroll
  for (int m0 = 0; m0 < 4; ++m0)
    #pragma unroll
    for (int nt = 0; nt < 2; ++nt) acc[m0][nt] = z4;
  #pragma unroll
  for (int s = 0; s < 4; ++s) {
    bf8 af[4], bfr[2];
    #pragma unroll
    for (int m0 = 0; m0 < 4; ++m0)
      af[m0] = *(const bf8*)&vs[(m0*16 + l16)*136 + s*32 + quad*8];
    #pragma unroll
    for (int nt = 0; nt < 2; ++nt)
      bfr[nt] = *(const bf8*)&ps[(w*32 + nt*16 + l16)*72 + s*32 + quad*8];
    #pragma unroll
    for (int m0 = 0; m0 < 4; ++m0)
      #pragma unroll
      for (int nt = 0; nt < 2; ++nt)
        acc[m0][nt] = MFMA(af[m0], bfr[nt], acc[m0][nt]);
  }
  __syncthreads();                      // ps reads done; reuse as out-stage

  __bf16* oS = (__bf16*)(smem + 21504 + 4352*w);   // [64][34] per wave
  #pragma unroll
  for (int m0 = 0; m0 < 4; ++m0)
    #pragma unroll
    for (int nt = 0; nt < 2; ++nt)
      #pragma unroll
      for (int rg = 0; rg < 4; ++rg)
        oS[(m0*16 + quad*4 + rg)*34 + nt*16 + l16] = (__bf16)acc[m0][nt][rg];
  // own-wave region only: no barrier needed
  ushort* dp = (ushort*)(dst + (size_t)b*1048576 + (size_t)r*128 + w*32);
  ushort* oSu = (ushort*)oS;
  for (int i = lane; i < 1024; i += 64) {
    int d = i >> 4, pp = (i & 15)*2;
    *(ushort2*)&dp[(size_t)d*16384 + pp] = *(ushort2*)&oSu[d*34 + pp];
  }
}

// Merge row stats (b,h,w) and col stats (b,w,h) -> per-pixel factors cW,cH.
__global__ __launch_bounds__(256) void scale_kernel(
    const float* __restrict__ mW, const float* __restrict__ sW,
    const float* __restrict__ mH, const float* __restrict__ sH,
    float* __restrict__ cW, float* __restrict__ cH) {
  __shared__ float tm[32][33], ts[32][33];
  int b = blockIdx.z;
  int x0 = blockIdx.x*32, y0 = blockIdx.y*32;
  const float* mh = mH + b*16384;
  const float* sh = sH + b*16384;
  for (int i = threadIdx.y; i < 32; i += 8) {
    tm[i][threadIdx.x] = mh[(y0 + i)*128 + x0 + threadIdx.x];
    ts[i][threadIdx.x] = sh[(y0 + i)*128 + x0 + threadIdx.x];
  }
  __syncthreads();
  for (int i = threadIdx.y; i < 32; i += 8) {
    int h = x0 + i, w2 = y0 + threadIdx.x;
    int idx = b*16384 + h*128 + w2;
    float mw = mW[idx], sw = sW[idx];
    float mhv = tm[threadIdx.x][i], shv = ts[threadIdx.x][i];
    float M = fmaxf(mw, mhv);
    float ew = __expf(mw - M), eh = __expf(mhv - M);
    float inv = 1.0f / (sw*ew + shv*eh);
    cW[idx] = ew*inv;
    cH[idx] = eh*inv;
  }
}

// Bo = gamma*(Bo*cW + oT^T*cH) + A (all bf16, fp32 math); optionally BoT.
// BoT may alias oT (tile staged to LDS before overwrite).
__global__ __launch_bounds__(256) void combineT_kernel(
    __bf16* __restrict__ Bo, const __bf16* oT,
    const __bf16* __restrict__ A, const float* __restrict__ cW,
    const float* __restrict__ cH, const float* __restrict__ gamma,
    __bf16* BoT, int writeT) {
  __shared__ float tile[32][33];
  __shared__ float rt[32][33];
  int n = blockIdx.z;                       // b*64 + d
  int b = n >> 6;
  int x0 = blockIdx.x*32, y0 = blockIdx.y*32;
  const __bf16* ip = oT + (size_t)n*16384;
  for (int i = threadIdx.y; i < 32; i += 8)
    tile[i][threadIdx.x] = (float)ip[(size_t)(y0 + i)*128 + x0 + threadIdx.x];
  __syncthreads();
  float g = *gamma;
  for (int i = threadIdx.y; i < 32; i += 8) {
    int h = x0 + i, w2 = y0 + threadIdx.x;
    size_t idx = (size_t)n*16384 + (size_t)h*128 + w2;
    int pix = b*16384 + h*128 + w2;
    float res = g*((float)Bo[idx]*cW[pix] + tile[threadIdx.x][i]*cH[pix])
                + (float)A[idx];
    Bo[idx] = (__bf16)res;
    rt[i][threadIdx.x] = res;               // value at (h=x0+i, w=y0+tx)
  }
  if (writeT) {
    __syncthreads();
    for (int i = threadIdx.y; i < 32; i += 8)
      BoT[(size_t)n*16384 + (size_t)(y0 + i)*128 + x0 + threadIdx.x] =
          (__bf16)rt[threadIdx.x][i];
  }
}

// MFMA pointwise 64->64 per (b,r) slice: out[o][p] = sum_c wpw[o][c]*A[c][p].
__global__ __launch_bounds__(256) void pw_kernel(
    const __bf16* __restrict__ A, const float* __restrict__ wpw,
    float* __restrict__ out) {
  __shared__ __align__(16) char smem[33792];
  __bf16* ys = (__bf16*)smem;               // [128][64] swizzled
  int t = threadIdx.x;
  int r = blockIdx.x, b = blockIdx.y;
  const ushort* sp = (const ushort*)(A + (size_t)b*1048576 + (size_t)r*128);
  for (int i = t; i < 4096; i += 256) {
    int p = i & 127, c = (i >> 7)*2;
    ushort u0 = sp[(size_t)c*16384 + p];
    ushort u1 = sp[(size_t)(c + 1)*16384 + p];
    int cs = c ^ ((p & 7) << 3);
    ushort2 uv; uv.x = u0; uv.y = u1;
    *(ushort2*)((ushort*)ys + p*64 + cs) = uv;
  }
  int lane = t & 63, w = t >> 6;
  int l16 = lane & 15, quad = lane >> 4;
  bf8 a_w[4][2];
  #pragma unroll
  for (int m0 = 0; m0 < 4; ++m0) {
    const float* wr = wpw + (m0*16 + l16)*64;
    #pragma unroll
    for (int s = 0; s < 2; ++s) {
      bf8 f;
      #pragma unroll
      for (int j = 0; j < 8; ++j) f[j] = (__bf16)wr[quad*8 + s*32 + j];
      a_w[m0][s] = f;
    }
  }
  __syncthreads();                     // ys staged
  bf8 b_ys[2][2];
  #pragma unroll
  for (int nt = 0; nt < 2; ++nt) {
    int p = w*32 + nt*16 + l16;
    #pragma unroll
    for (int s = 0; s < 2; ++s)
      b_ys[nt][s] = *(const bf8*)&ys[p*64 + ((s*32 + quad*8) ^ ((p & 7) << 3))];
  }
  __syncthreads();                     // all frag loads done; ys dead
  f4 z4 = {0.f, 0.f, 0.f, 0.f};
  f4 acc[4][2];
  #pragma unroll
  for (int m0 = 0; m0 < 4; ++m0)
    #pragma unroll
    for (int nt = 0; nt < 2; ++nt) {
      f4 a2 = z4;
      a2 = MFMA(a_w[m0][0], b_ys[nt][0], a2);
      a2 = MFMA(a_w[m0][1], b_ys[nt][1], a2);
      acc[m0][nt] = a2;
    }
  float* oS = (float*)(smem + 8448*w);  // [64][33] fp32, wave-local
  #pragma unroll
  for (int m0 = 0; m0 < 4; ++m0)
    #pragma unroll
    for (int nt = 0; nt < 2; ++nt)
      #pragma unroll
      for (int rg = 0; rg < 4; ++rg)
        oS[(m0*16 + quad*4 + rg)*33 + nt*16 + l16] = acc[m0][nt][rg];
  float* dp = out + (size_t)b*1048576 + (size_t)r*128 + w*32;
  for (int i = lane; i < 2048; i += 64) {
    int d = i >> 5, pp = i & 31;
    dp[(size_t)d*16384 + pp] = oS[d*33 + pp];
  }
}

extern "C" void kernel_launch(void* const* d_in, const int* in_sizes, int n_in,
                              void* d_out, int out_size, void* d_ws, size_t ws_size,
                              hipStream_t stream) {
  const float* x     = (const float*)d_in[0];
  const float* wdw   = (const float*)d_in[1];
  const float* wq    = (const float*)d_in[2];
  const float* wk    = (const float*)d_in[3];
  const float* wv    = (const float*)d_in[4];
  const float* gamma = (const float*)d_in[5];
  const float* wpw   = (const float*)d_in[6];
  float* out = (float*)d_out;

  // Workspace (bf16 elems unless noted): y,z,AT,vR,vT 8388608 each;
  // qR,kR,qT,kT 1048576 each; 6 fp32 stat planes.  Total ~95.4 MB.
  __bf16* y  = (__bf16*)d_ws;
  __bf16* z  = y  + 8388608;
  __bf16* AT = z  + 8388608;
  __bf16* qR = AT + 8388608;
  __bf16* kR = qR + 1048576;
  __bf16* qT = kR + 1048576;
  __bf16* kT = qT + 1048576;
  __bf16* vR = kT + 1048576;
  __bf16* vT = vR + 8388608;
  float* mW = (float*)(vT + 8388608);
  float* sW = mW + 131072;
  float* mH = sW + 131072;
  float* sH = mH + 131072;
  float* cW = sH + 131072;
  float* cH = cW + 131072;
  size_t need = ((size_t)5*8388608 + 4*1048576)*2 + (size_t)6*131072*4;
  if (ws_size < need) return;

  dwconv_kernel<<<dim3(4, 4, 512), 256, 0, stream>>>(x, wdw, y, AT);

  for (int pass = 0; pass < 2; ++pass) {
    const __bf16* A = pass ? z : y;   // CCA input / residual
    __bf16* Bo      = pass ? y : z;   // CCA output

    proj_kernel<<<dim3(128, 8, 2), 256, 0, stream>>>(
        A, AT, wq, wk, wv, qR, kR, vR, qT, kT, vT);
    attn_kernel<<<dim3(128, 8, 2), 256, 0, stream>>>(
        qR, kR, vR, qT, kT, vT, Bo, AT, mW, sW, mH, sH);
    scale_kernel<<<dim3(4, 4, 8), dim3(32, 8), 0, stream>>>(mW, sW, mH, sH, cW, cH);
    // pass 0: also write Bo^T into AT (becomes next pass's transposed input)
    combineT_kernel<<<dim3(4, 4, 512), dim3(32, 8), 0, stream>>>(
        Bo, AT, A, cW, cH, gamma, AT, pass == 0 ? 1 : 0);
  }

  pw_kernel<<<dim3(128, 8), 256, 0, stream>>>(y, wpw, out);
}

// Round 7
// 252.992 us; speedup vs baseline: 1.2115x; 1.2115x over previous
//
#include <hip/hip_runtime.h>

// B=8, C=64, D=8 (q/k), H=W=128.  dwconv3x3 -> CCA -> CCA -> pointwise.
// Round 6: fused ccdir with only TWO barriers (stage->proj, proj->consume);
// E/softmax/O/store run barrier-free (ps rows + out-stage are wave-private).
// ps stride fixed to 136 (r5 had overlapping 72-stride rows = latent bug).
// Weights pre-packed per-lane in MFMA A-frag layout by prep_weights (runs
// every call); scale fused into combineT.  All intermediates bf16.
// Fragment layouts (mfma_f32_16x16x32_bf16):
//   A[m=lane&15][k=quad*8+j (+32s)], B[k][n=lane&15], C col=lane&15,row=quad*4+reg

#define NEGINF -3.0e38f

typedef __attribute__((ext_vector_type(8))) __bf16 bf8;
typedef __attribute__((ext_vector_type(4))) float f4;

__device__ __forceinline__ f4 MFMA(bf8 a, bf8 b, f4 c) {
  return __builtin_amdgcn_mfma_f32_16x16x32_bf16(a, b, c, 0, 0, 0);
}
__device__ __forceinline__ ushort bfb(float f) {
  __bf16 h = (__bf16)f;
  return *(ushort*)&h;
}

// Pack wq/wk/wv and wpw into per-lane A-fragment tables, [frag][lane] layout
// so each frag load in the hot kernels is one coalesced dwordx4.
// wtab frags: 0..1 = qk s=0,1 ; 2+m0*2+s = wv[m0][s].  ptab: m0*2+s.
__global__ __launch_bounds__(64) void prep_weights(
    const float* __restrict__ wq, const float* __restrict__ wk,
    const float* __restrict__ wv, const float* __restrict__ wpw,
    __bf16* __restrict__ wtab, __bf16* __restrict__ ptab) {
  int lane = threadIdx.x;
  int l16 = lane & 15, quad = lane >> 4;
  const float* wr = (l16 < 8) ? (wq + l16*64) : (wk + (l16 - 8)*64);
  for (int s = 0; s < 2; ++s)
    for (int j = 0; j < 8; ++j)
      wtab[(s*64 + lane)*8 + j] = (__bf16)wr[quad*8 + s*32 + j];
  for (int m0 = 0; m0 < 4; ++m0) {
    const float* vr = wv + (m0*16 + l16)*64;
    const float* pr = wpw + (m0*16 + l16)*64;
    for (int s = 0; s < 2; ++s)
      for (int j = 0; j < 8; ++j) {
        wtab[((2 + m0*2 + s)*64 + lane)*8 + j] = (__bf16)vr[quad*8 + s*32 + j];
        ptab[((m0*2 + s)*64 + lane)*8 + j]     = (__bf16)pr[quad*8 + s*32 + j];
      }
  }
}

// 32x32-tile dwconv3x3; writes y and yT (bf16), packed ushort2 stores.
__global__ __launch_bounds__(256) void dwconv_kernel(
    const float* __restrict__ x, const float* __restrict__ wdw,
    __bf16* __restrict__ y, __bf16* __restrict__ yT) {
  __shared__ float in[34][36];
  __shared__ float ot[32][33];
  int tx = threadIdx.x & 31, ty = threadIdx.x >> 5;   // 32x8
  int w0 = blockIdx.x*32, h0 = blockIdx.y*32;
  int n = blockIdx.z;                                  // b*64 + c
  const float* xp = x + (size_t)n*16384;
  const float* wp = wdw + (n & 63)*9;
  float wr[9];
  #pragma unroll
  for (int j = 0; j < 9; ++j) wr[j] = wp[j];
  for (int i = ty; i < 34; i += 8) {
    int hh = h0 + i - 1;
    for (int j = tx; j < 34; j += 32) {
      int ww = w0 + j - 1;
      float v = 0.f;
      if (hh >= 0 && hh < 128 && ww >= 0 && ww < 128) v = xp[hh*128 + ww];
      in[i][j] = v;
    }
  }
  __syncthreads();
  for (int i2 = ty; i2 < 32; i2 += 8) {
    float acc = 0.f;
    #pragma unroll
    for (int kh = 0; kh < 3; ++kh)
      #pragma unroll
      for (int kw = 0; kw < 3; ++kw)
        acc += wr[kh*3 + kw]*in[i2 + kh][tx + kw];
    ot[i2][tx] = acc;
  }
  __syncthreads();
  ushort* yp  = (ushort*)(y  + (size_t)n*16384);
  ushort* ytp = (ushort*)(yT + (size_t)n*16384);
  for (int idx = threadIdx.x; idx < 512; idx += 256) {
    int row = idx >> 4, c2 = (idx & 15)*2;
    ushort2 u;
    u.x = bfb(ot[row][c2]); u.y = bfb(ot[row][c2 + 1]);
    *(ushort2*)&yp[(size_t)(h0 + row)*128 + w0 + c2] = u;
    ushort2 v;
    v.x = bfb(ot[c2][row]); v.y = bfb(ot[c2 + 1][row]);
    *(ushort2*)&ytp[(size_t)(w0 + row)*128 + h0 + c2] = v;
  }
}

// Fused CCA direction kernel, two barriers.
// dir=0: src=A -> dstRow, stats mW,sW.  dir=1: src=dst=AT in place (slice
// fully staged before overwrite), diag mask, stats mH,sH.
// Output UNNORMALIZED: O[d][p] = sum_c exp(e(p,c)-m[p]) * v[d][c].
__global__ __launch_bounds__(256) void ccdir_kernel(
    const __bf16* __restrict__ srcRow, __bf16* __restrict__ dstRow,
    __bf16* __restrict__ srcdstCol,
    const __bf16* __restrict__ wtab,
    float* __restrict__ mW, float* __restrict__ sW,
    float* __restrict__ mH, float* __restrict__ sH) {
  // LDS: vs[64][136]b @0 (17408); qs[128][8]b @17408; ks @19456;
  // ps[128][136]b @21504 (34816; ys[128][72]b aliases it, dead pre-B1;
  // per-wave bf16 out-stage [64][34] aliases own ps rows).  Total 56320.
  __shared__ __align__(16) char smem[56320];
  __bf16* vs = (__bf16*)smem;
  __bf16* qs = (__bf16*)(smem + 17408);
  __bf16* ks = (__bf16*)(smem + 19456);
  __bf16* ys = (__bf16*)(smem + 21504);
  __bf16* ps = (__bf16*)(smem + 21504);

  int t = threadIdx.x;
  int r = blockIdx.x, b = blockIdx.y, dir = blockIdx.z;
  const __bf16* src = dir ? srcdstCol : srcRow;
  __bf16* dst       = dir ? srcdstCol : dstRow;
  float* mo         = dir ? mH : mW;
  float* so         = dir ? sH : sW;
  const ushort* sp = (const ushort*)(src + (size_t)b*1048576 + (size_t)r*128);

  int lane = t & 63, w = t >> 6;
  int l16 = lane & 15, quad = lane >> 4;

  // ---- phase 0: stage Y[c][p] -> ys[p][c] (stride 72) + weight frags ----
  for (int i = t; i < 4096; i += 256) {
    int p = i & 127, c = (i >> 7)*2;
    ushort2 uv;
    uv.x = sp[(size_t)c*16384 + p];
    uv.y = sp[(size_t)(c + 1)*16384 + p];
    *(ushort2*)((ushort*)ys + p*72 + c) = uv;
  }
  bf8 a_qk[2], a_wv[4][2];
  #pragma unroll
  for (int s = 0; s < 2; ++s)
    a_qk[s] = *(const bf8*)&wtab[(s*64 + lane)*8];
  #pragma unroll
  for (int m0 = 0; m0 < 4; ++m0)
    #pragma unroll
    for (int s = 0; s < 2; ++s)
      a_wv[m0][s] = *(const bf8*)&wtab[((2 + m0*2 + s)*64 + lane)*8];
  __syncthreads();                      // B0: ys staged

  // ---- phase 1: projections (wave owns p-block [32w, 32w+32)) ----
  f4 z4 = {0.f, 0.f, 0.f, 0.f};
  bf8 b_ys[2][2];
  #pragma unroll
  for (int nt = 0; nt < 2; ++nt) {
    int p = w*32 + nt*16 + l16;
    #pragma unroll
    for (int s = 0; s < 2; ++s)
      b_ys[nt][s] = *(const bf8*)&ys[p*72 + s*32 + quad*8];
  }
  #pragma unroll
  for (int nt = 0; nt < 2; ++nt) {
    int p = w*32 + nt*16 + l16;
    f4 aqk = z4;
    aqk = MFMA(a_qk[0], b_ys[nt][0], aqk);
    aqk = MFMA(a_qk[1], b_ys[nt][1], aqk);
    __bf16* dp8 = ((quad < 2) ? qs : ks) + p*8 + (quad & 1)*4;
    #pragma unroll
    for (int rg = 0; rg < 4; ++rg) dp8[rg] = (__bf16)aqk[rg];
  }
  #pragma unroll
  for (int m0 = 0; m0 < 4; ++m0)
    #pragma unroll
    for (int nt = 0; nt < 2; ++nt) {
      f4 va = z4;
      va = MFMA(a_wv[m0][0], b_ys[nt][0], va);
      va = MFMA(a_wv[m0][1], b_ys[nt][1], va);
      int u = w*32 + nt*16 + l16;
      #pragma unroll
      for (int rg = 0; rg < 4; ++rg)
        vs[(m0*16 + quad*4 + rg)*136 + u] = (__bf16)va[rg];
    }
  __syncthreads();                      // B1: qs/ks/vs visible; ys dead

  // ---- barrier-free tail: E -> softmax -> O -> store ----
  bf8 zb;
  #pragma unroll
  for (int j = 0; j < 8; ++j) zb[j] = (__bf16)0.f;
  int sb = ((b*128 + r) << 7);
  #pragma unroll
  for (int mt = 0; mt < 2; ++mt) {
    int p = w*32 + mt*16 + l16;
    bf8 aq = (quad == 0) ? *(const bf8*)&qs[p*8] : zb;
    f4 e[8];
    #pragma unroll
    for (int nt = 0; nt < 8; ++nt) {
      bf8 bk = (quad == 0) ? *(const bf8*)&ks[(nt*16 + l16)*8] : zb;
      e[nt] = MFMA(aq, bk, z4);
    }
    if (dir) {                          // diag mask: c == p
      #pragma unroll
      for (int nt = 0; nt < 8; ++nt)
        #pragma unroll
        for (int rg = 0; rg < 4; ++rg)
          if (nt == 2*w + mt && l16 == quad*4 + rg) e[nt][rg] = NEGINF;
    }
    float mx[4], sm[4];
    #pragma unroll
    for (int rg = 0; rg < 4; ++rg) {
      float m2 = e[0][rg];
      #pragma unroll
      for (int nt = 1; nt < 8; ++nt) m2 = fmaxf(m2, e[nt][rg]);
      #pragma unroll
      for (int d2 = 1; d2 < 16; d2 <<= 1) m2 = fmaxf(m2, __shfl_xor(m2, d2, 64));
      mx[rg] = m2;
      sm[rg] = 0.f;
    }
    int prow = w*32 + mt*16 + quad*4;
    #pragma unroll
    for (int nt = 0; nt < 8; ++nt)
      #pragma unroll
      for (int rg = 0; rg < 4; ++rg) {
        float pv = __expf(e[nt][rg] - mx[rg]);
        sm[rg] += pv;
        ps[(prow + rg)*136 + nt*16 + l16] = (__bf16)pv;   // own-wave rows
      }
    #pragma unroll
    for (int rg = 0; rg < 4; ++rg) {
      float s2 = sm[rg];
      #pragma unroll
      for (int d2 = 1; d2 < 16; d2 <<= 1) s2 += __shfl_xor(s2, d2, 64);
      if (l16 == 0) {
        mo[sb + prow + rg] = mx[rg];
        so[sb + prow + rg] = s2;
      }
    }
  }

  // O = V x P^T  (M=64 d, N=32 p per wave, K=128); ps reads are own-wave rows
  f4 acc[4][2];
  #pragma unroll
  for (int m0 = 0; m0 < 4; ++m0)
    #pragma unroll
    for (int nt = 0; nt < 2; ++nt) acc[m0][nt] = z4;
  #pragma unroll
  for (int s = 0; s < 4; ++s) {
    bf8 af[4], bfr[2];
    #pragma unroll
    for (int m0 = 0; m0 < 4; ++m0)
      af[m0] = *(const bf8*)&vs[(m0*16 + l16)*136 + s*32 + quad*8];
    #pragma unroll
    for (int nt = 0; nt < 2; ++nt)
      bfr[nt] = *(const bf8*)&ps[(w*32 + nt*16 + l16)*136 + s*32 + quad*8];
    #pragma unroll
    for (int m0 = 0; m0 < 4; ++m0)
      #pragma unroll
      for (int nt = 0; nt < 2; ++nt)
        acc[m0][nt] = MFMA(af[m0], bfr[nt], acc[m0][nt]);
  }

  // out-stage in own-wave ps block (wave-private; no barrier needed)
  __bf16* oS = (__bf16*)(smem + 21504 + 8704*w);   // [64][34] bf16
  #pragma unroll
  for (int m0 = 0; m0 < 4; ++m0)
    #pragma unroll
    for (int nt = 0; nt < 2; ++nt)
      #pragma unroll
      for (int rg = 0; rg < 4; ++rg)
        oS[(m0*16 + quad*4 + rg)*34 + nt*16 + l16] = (__bf16)acc[m0][nt][rg];
  ushort* dp = (ushort*)(dst + (size_t)b*1048576 + (size_t)r*128 + w*32);
  ushort* oSu = (ushort*)oS;
  for (int i = lane; i < 1024; i += 64) {
    int d = i >> 4, pp = (i & 15)*2;
    *(ushort2*)&dp[(size_t)d*16384 + pp] = *(ushort2*)&oSu[d*34 + pp];
  }
}

// Fused scale+combine:  Bo = gamma*(Bo*cW + oT^T*cH) + A, with
// cW,cH computed inline from stats (flash two-block merge).  Optionally
// writes Bo^T into BoT (may alias oT; tile staged to LDS first).
__global__ __launch_bounds__(256) void combineT_kernel(
    __bf16* __restrict__ Bo, const __bf16* oT,
    const __bf16* __restrict__ A,
    const float* __restrict__ mW, const float* __restrict__ sW,
    const float* __restrict__ mH, const float* __restrict__ sH,
    const float* __restrict__ gamma, __bf16* BoT, int writeT) {
  __shared__ float tile[32][33], tm[32][33], ts[32][33];
  __shared__ float rt[32][33];
  int n = blockIdx.z;                       // b*64 + d
  int b = n >> 6;
  int x0 = blockIdx.x*32, y0 = blockIdx.y*32;
  const __bf16* ip = oT + (size_t)n*16384;
  const float* mhp = mH + b*16384;
  const float* shp = sH + b*16384;
  for (int i = threadIdx.y; i < 32; i += 8) {
    tile[i][threadIdx.x] = (float)ip[(size_t)(y0 + i)*128 + x0 + threadIdx.x];
    tm[i][threadIdx.x] = mhp[(y0 + i)*128 + x0 + threadIdx.x];
    ts[i][threadIdx.x] = shp[(y0 + i)*128 + x0 + threadIdx.x];
  }
  __syncthreads();
  float g = *gamma;
  for (int i = threadIdx.y; i < 32; i += 8) {
    int h = x0 + i, w2 = y0 + threadIdx.x;
    size_t idx = (size_t)n*16384 + (size_t)h*128 + w2;
    int pix = b*16384 + h*128 + w2;
    float mw = mW[pix], sw = sW[pix];
    float mh = tm[threadIdx.x][i], sh = ts[threadIdx.x][i];
    float M = fmaxf(mw, mh);
    float ew = __expf(mw - M), eh = __expf(mh - M);
    float inv = 1.0f / (sw*ew + sh*eh);
    float res = g*((float)Bo[idx]*ew*inv + tile[threadIdx.x][i]*eh*inv)
                + (float)A[idx];
    Bo[idx] = (__bf16)res;
    rt[i][threadIdx.x] = res;               // (h=x0+i, w=y0+tx)
  }
  if (writeT) {
    __syncthreads();
    for (int i = threadIdx.y; i < 32; i += 8)
      BoT[(size_t)n*16384 + (size_t)(y0 + i)*128 + x0 + threadIdx.x] =
          (__bf16)rt[threadIdx.x][i];
  }
}

// MFMA pointwise 64->64 per (b,r) slice: out[o][p] = sum_c wpw[o][c]*A[c][p].
__global__ __launch_bounds__(256) void pw_kernel(
    const __bf16* __restrict__ A, const __bf16* __restrict__ ptab,
    float* __restrict__ out) {
  __shared__ __align__(16) char smem[33792];
  __bf16* ys = (__bf16*)smem;               // [128][72]
  int t = threadIdx.x;
  int r = blockIdx.x, b = blockIdx.y;
  const ushort* sp = (const ushort*)(A + (size_t)b*1048576 + (size_t)r*128);
  for (int i = t; i < 4096; i += 256) {
    int p = i & 127, c = (i >> 7)*2;
    ushort2 uv;
    uv.x = sp[(size_t)c*16384 + p];
    uv.y = sp[(size_t)(c + 1)*16384 + p];
    *(ushort2*)((ushort*)ys + p*72 + c) = uv;
  }
  int lane = t & 63, w = t >> 6;
  int l16 = lane & 15, quad = lane >> 4;
  bf8 a_w[4][2];
  #pragma unroll
  for (int m0 = 0; m0 < 4; ++m0)
    #pragma unroll
    for (int s = 0; s < 2; ++s)
      a_w[m0][s] = *(const bf8*)&ptab[((m0*2 + s)*64 + lane)*8];
  __syncthreads();                     // ys staged
  bf8 b_ys[2][2];
  #pragma unroll
  for (int nt = 0; nt < 2; ++nt) {
    int p = w*32 + nt*16 + l16;
    #pragma unroll
    for (int s = 0; s < 2; ++s)
      b_ys[nt][s] = *(const bf8*)&ys[p*72 + s*32 + quad*8];
  }
  __syncthreads();                     // all frag loads done; ys dead
  f4 z4 = {0.f, 0.f, 0.f, 0.f};
  f4 acc[4][2];
  #pragma unroll
  for (int m0 = 0; m0 < 4; ++m0)
    #pragma unroll
    for (int nt = 0; nt < 2; ++nt) {
      f4 a2 = z4;
      a2 = MFMA(a_w[m0][0], b_ys[nt][0], a2);
      a2 = MFMA(a_w[m0][1], b_ys[nt][1], a2);
      acc[m0][nt] = a2;
    }
  float* oS = (float*)(smem + 8448*w);  // [64][33] fp32, wave-local
  #pragma unroll
  for (int m0 = 0; m0 < 4; ++m0)
    #pragma unroll
    for (int nt = 0; nt < 2; ++nt)
      #pragma unroll
      for (int rg = 0; rg < 4; ++rg)
        oS[(m0*16 + quad*4 + rg)*33 + nt*16 + l16] = acc[m0][nt][rg];
  float* dp = out + (size_t)b*1048576 + (size_t)r*128 + w*32;
  for (int i = lane; i < 2048; i += 64) {
    int d = i >> 5, pp = i & 31;
    dp[(size_t)d*16384 + pp] = oS[d*33 + pp];
  }
}

extern "C" void kernel_launch(void* const* d_in, const int* in_sizes, int n_in,
                              void* d_out, int out_size, void* d_ws, size_t ws_size,
                              hipStream_t stream) {
  const float* x     = (const float*)d_in[0];
  const float* wdw   = (const float*)d_in[1];
  const float* wq    = (const float*)d_in[2];
  const float* wk    = (const float*)d_in[3];
  const float* wv    = (const float*)d_in[4];
  const float* gamma = (const float*)d_in[5];
  const float* wpw   = (const float*)d_in[6];
  float* out = (float*)d_out;

  // Workspace: y,z,AT bf16 (16 MB each) + wtab/ptab + 4 fp32 stat planes.
  __bf16* y    = (__bf16*)d_ws;
  __bf16* z    = y + 8388608;
  __bf16* AT   = z + 8388608;
  __bf16* wtab = AT + 8388608;        // 10 frags x 64 lanes x 8 = 5120
  __bf16* ptab = wtab + 5120;         // 8 frags x 64 lanes x 8 = 4096
  float* mW = (float*)(ptab + 4096);
  float* sW = mW + 131072;
  float* mH = sW + 131072;
  float* sH = mH + 131072;
  size_t need = (size_t)3*8388608*2 + (5120 + 4096)*2 + (size_t)4*131072*4;
  if (ws_size < need) return;

  prep_weights<<<1, 64, 0, stream>>>(wq, wk, wv, wpw, wtab, ptab);
  dwconv_kernel<<<dim3(4, 4, 512), 256, 0, stream>>>(x, wdw, y, AT);

  for (int pass = 0; pass < 2; ++pass) {
    const __bf16* A = pass ? z : y;   // CCA input / residual
    __bf16* Bo      = pass ? y : z;   // CCA output

    ccdir_kernel<<<dim3(128, 8, 2), 256, 0, stream>>>(
        A, Bo, AT, wtab, mW, sW, mH, sH);
    // pass 0: also write Bo^T into AT (next pass's transposed input)
    combineT_kernel<<<dim3(4, 4, 512), dim3(32, 8), 0, stream>>>(
        Bo, AT, A, mW, sW, mH, sH, gamma, AT, pass == 0 ? 1 : 0);
  }

  pw_kernel<<<dim3(128, 8), 256, 0, stream>>>(y, ptab, out);
}

// Round 8
// 229.964 us; speedup vs baseline: 1.3328x; 1.1001x over previous
//
#include <hip/hip_runtime.h>

// B=8, C=64, D=8 (q/k), H=W=128.  dwconv3x3 -> CCA -> CCA -> pointwise.
// Round 7: ccdir drops softmax max-subtraction (scores are O(10); softmax is
// shift-invariant, so P=exp(e), S=sum exp, merge=1/(sW+sH) is exact) and
// streams P in two 64-col halves -> ps is [128][72]b16, LDS 39936 B ->
// 4 blocks/CU.  Two barriers total; E/P/O tail is barrier-free (ps rows and
// out-stage are wave-private).  Weights pre-packed in A-frag layout.
// Fragment layouts (mfma_f32_16x16x32_bf16):
//   A[m=lane&15][k=quad*8+j (+32s)], B[k][n=lane&15], C col=lane&15,row=quad*4+reg

#define NEGINF -3.0e38f

typedef __attribute__((ext_vector_type(8))) __bf16 bf8;
typedef __attribute__((ext_vector_type(4))) float f4;

__device__ __forceinline__ f4 MFMA(bf8 a, bf8 b, f4 c) {
  return __builtin_amdgcn_mfma_f32_16x16x32_bf16(a, b, c, 0, 0, 0);
}
__device__ __forceinline__ ushort bfb(float f) {
  __bf16 h = (__bf16)f;
  return *(ushort*)&h;
}

// Pack wq/wk/wv and wpw into per-lane A-fragment tables, [frag][lane] layout
// so each frag load in the hot kernels is one coalesced dwordx4.
__global__ __launch_bounds__(64) void prep_weights(
    const float* __restrict__ wq, const float* __restrict__ wk,
    const float* __restrict__ wv, const float* __restrict__ wpw,
    __bf16* __restrict__ wtab, __bf16* __restrict__ ptab) {
  int lane = threadIdx.x;
  int l16 = lane & 15, quad = lane >> 4;
  const float* wr = (l16 < 8) ? (wq + l16*64) : (wk + (l16 - 8)*64);
  for (int s = 0; s < 2; ++s)
    for (int j = 0; j < 8; ++j)
      wtab[(s*64 + lane)*8 + j] = (__bf16)wr[quad*8 + s*32 + j];
  for (int m0 = 0; m0 < 4; ++m0) {
    const float* vr = wv + (m0*16 + l16)*64;
    const float* pr = wpw + (m0*16 + l16)*64;
    for (int s = 0; s < 2; ++s)
      for (int j = 0; j < 8; ++j) {
        wtab[((2 + m0*2 + s)*64 + lane)*8 + j] = (__bf16)vr[quad*8 + s*32 + j];
        ptab[((m0*2 + s)*64 + lane)*8 + j]     = (__bf16)pr[quad*8 + s*32 + j];
      }
  }
}

// 32x32-tile dwconv3x3; writes y and yT (bf16), packed ushort2 stores.
__global__ __launch_bounds__(256) void dwconv_kernel(
    const float* __restrict__ x, const float* __restrict__ wdw,
    __bf16* __restrict__ y, __bf16* __restrict__ yT) {
  __shared__ float in[34][36];
  __shared__ float ot[32][33];
  int tx = threadIdx.x & 31, ty = threadIdx.x >> 5;   // 32x8
  int w0 = blockIdx.x*32, h0 = blockIdx.y*32;
  int n = blockIdx.z;                                  // b*64 + c
  const float* xp = x + (size_t)n*16384;
  const float* wp = wdw + (n & 63)*9;
  float wr[9];
  #pragma unroll
  for (int j = 0; j < 9; ++j) wr[j] = wp[j];
  for (int i = ty; i < 34; i += 8) {
    int hh = h0 + i - 1;
    for (int j = tx; j < 34; j += 32) {
      int ww = w0 + j - 1;
      float v = 0.f;
      if (hh >= 0 && hh < 128 && ww >= 0 && ww < 128) v = xp[hh*128 + ww];
      in[i][j] = v;
    }
  }
  __syncthreads();
  for (int i2 = ty; i2 < 32; i2 += 8) {
    float acc = 0.f;
    #pragma unroll
    for (int kh = 0; kh < 3; ++kh)
      #pragma unroll
      for (int kw = 0; kw < 3; ++kw)
        acc += wr[kh*3 + kw]*in[i2 + kh][tx + kw];
    ot[i2][tx] = acc;
  }
  __syncthreads();
  ushort* yp  = (ushort*)(y  + (size_t)n*16384);
  ushort* ytp = (ushort*)(yT + (size_t)n*16384);
  for (int idx = threadIdx.x; idx < 512; idx += 256) {
    int row = idx >> 4, c2 = (idx & 15)*2;
    ushort2 u;
    u.x = bfb(ot[row][c2]); u.y = bfb(ot[row][c2 + 1]);
    *(ushort2*)&yp[(size_t)(h0 + row)*128 + w0 + c2] = u;
    ushort2 v;
    v.x = bfb(ot[c2][row]); v.y = bfb(ot[c2 + 1][row]);
    *(ushort2*)&ytp[(size_t)(w0 + row)*128 + h0 + c2] = v;
  }
}

// Fused CCA direction kernel, two barriers, no max-subtract.
// dir=0: src=A -> dstRow, stats sW.  dir=1: src=dst=AT in place, diag mask,
// stats sH.  Output UNNORMALIZED: O[d][p] = sum_c exp(e(p,c)) * v[d][c].
__global__ __launch_bounds__(256) void ccdir_kernel(
    const __bf16* __restrict__ srcRow, __bf16* __restrict__ dstRow,
    __bf16* __restrict__ srcdstCol,
    const __bf16* __restrict__ wtab,
    float* __restrict__ sW, float* __restrict__ sH) {
  // LDS: vs[64][136]b @0 (17408); qs[128][8]b @17408; ks @19456;
  // ps[128][72]b @21504 (18432; ys[128][72]b aliases it, dead pre-B1;
  // per-wave bf16 out-stage [64][34] (4352) fits own ps rows [32][72]=4608).
  // Total 39936 -> 4 blocks/CU.
  __shared__ __align__(16) char smem[39936];
  __bf16* vs = (__bf16*)smem;
  __bf16* qs = (__bf16*)(smem + 17408);
  __bf16* ks = (__bf16*)(smem + 19456);
  __bf16* ys = (__bf16*)(smem + 21504);
  __bf16* ps = (__bf16*)(smem + 21504);

  int t = threadIdx.x;
  int r = blockIdx.x, b = blockIdx.y, dir = blockIdx.z;
  const __bf16* src = dir ? srcdstCol : srcRow;
  __bf16* dst       = dir ? srcdstCol : dstRow;
  float* so         = dir ? sH : sW;
  const ushort* sp = (const ushort*)(src + (size_t)b*1048576 + (size_t)r*128);

  int lane = t & 63, w = t >> 6;
  int l16 = lane & 15, quad = lane >> 4;

  // ---- phase 0: stage Y[c][p] -> ys[p][c] (stride 72) + weight frags ----
  for (int i = t; i < 4096; i += 256) {
    int p = i & 127, c = (i >> 7)*2;
    ushort2 uv;
    uv.x = sp[(size_t)c*16384 + p];
    uv.y = sp[(size_t)(c + 1)*16384 + p];
    *(ushort2*)((ushort*)ys + p*72 + c) = uv;
  }
  bf8 a_qk[2], a_wv[4][2];
  #pragma unroll
  for (int s = 0; s < 2; ++s)
    a_qk[s] = *(const bf8*)&wtab[(s*64 + lane)*8];
  #pragma unroll
  for (int m0 = 0; m0 < 4; ++m0)
    #pragma unroll
    for (int s = 0; s < 2; ++s)
      a_wv[m0][s] = *(const bf8*)&wtab[((2 + m0*2 + s)*64 + lane)*8];
  __syncthreads();                      // B0: ys staged

  // ---- phase 1: projections (wave owns p-block [32w, 32w+32)) ----
  f4 z4 = {0.f, 0.f, 0.f, 0.f};
  bf8 b_ys[2][2];
  #pragma unroll
  for (int nt = 0; nt < 2; ++nt) {
    int p = w*32 + nt*16 + l16;
    #pragma unroll
    for (int s = 0; s < 2; ++s)
      b_ys[nt][s] = *(const bf8*)&ys[p*72 + s*32 + quad*8];
  }
  #pragma unroll
  for (int nt = 0; nt < 2; ++nt) {
    int p = w*32 + nt*16 + l16;
    f4 aqk = z4;
    aqk = MFMA(a_qk[0], b_ys[nt][0], aqk);
    aqk = MFMA(a_qk[1], b_ys[nt][1], aqk);
    __bf16* dp8 = ((quad < 2) ? qs : ks) + p*8 + (quad & 1)*4;
    #pragma unroll
    for (int rg = 0; rg < 4; ++rg) dp8[rg] = (__bf16)aqk[rg];
  }
  #pragma unroll
  for (int m0 = 0; m0 < 4; ++m0)
    #pragma unroll
    for (int nt = 0; nt < 2; ++nt) {
      f4 va = z4;
      va = MFMA(a_wv[m0][0], b_ys[nt][0], va);
      va = MFMA(a_wv[m0][1], b_ys[nt][1], va);
      int u = w*32 + nt*16 + l16;
      #pragma unroll
      for (int rg = 0; rg < 4; ++rg)
        vs[(m0*16 + quad*4 + rg)*136 + u] = (__bf16)va[rg];
    }
  __syncthreads();                      // B1: qs/ks/vs visible; ys dead

  // ---- barrier-free tail: per c-half { E -> P -> partial O } ----
  bf8 zb;
  #pragma unroll
  for (int j = 0; j < 8; ++j) zb[j] = (__bf16)0.f;
  bf8 aq[2];
  #pragma unroll
  for (int mt = 0; mt < 2; ++mt) {
    int p = w*32 + mt*16 + l16;
    aq[mt] = (quad == 0) ? *(const bf8*)&qs[p*8] : zb;
  }
  f4 acc[4][2];
  #pragma unroll
  for (int m0 = 0; m0 < 4; ++m0)
    #pragma unroll
    for (int nt = 0; nt < 2; ++nt) acc[m0][nt] = z4;
  float sm[2][4] = {{0.f,0.f,0.f,0.f},{0.f,0.f,0.f,0.f}};

  #pragma unroll
  for (int half = 0; half < 2; ++half) {
    #pragma unroll
    for (int mt = 0; mt < 2; ++mt) {
      f4 e[4];
      #pragma unroll
      for (int nt2 = 0; nt2 < 4; ++nt2) {
        int nt = half*4 + nt2;
        bf8 bk = (quad == 0) ? *(const bf8*)&ks[(nt*16 + l16)*8] : zb;
        e[nt2] = MFMA(aq[mt], bk, z4);
      }
      if (dir) {                        // diag mask: c == p
        #pragma unroll
        for (int nt2 = 0; nt2 < 4; ++nt2)
          #pragma unroll
          for (int rg = 0; rg < 4; ++rg)
            if (half*4 + nt2 == 2*w + mt && l16 == quad*4 + rg)
              e[nt2][rg] = NEGINF;
      }
      int prow = w*32 + mt*16 + quad*4;
      #pragma unroll
      for (int nt2 = 0; nt2 < 4; ++nt2)
        #pragma unroll
        for (int rg = 0; rg < 4; ++rg) {
          float pv = __expf(e[nt2][rg]);
          sm[mt][rg] += pv;
          ps[(prow + rg)*72 + nt2*16 + l16] = (__bf16)pv;   // own-wave rows
        }
    }
    #pragma unroll
    for (int s2 = 0; s2 < 2; ++s2) {
      int c0 = half*64 + s2*32;
      bf8 af[4], bfr[2];
      #pragma unroll
      for (int m0 = 0; m0 < 4; ++m0)
        af[m0] = *(const bf8*)&vs[(m0*16 + l16)*136 + c0 + quad*8];
      #pragma unroll
      for (int nt = 0; nt < 2; ++nt)
        bfr[nt] = *(const bf8*)&ps[(w*32 + nt*16 + l16)*72 + s2*32 + quad*8];
      #pragma unroll
      for (int m0 = 0; m0 < 4; ++m0)
        #pragma unroll
        for (int nt = 0; nt < 2; ++nt)
          acc[m0][nt] = MFMA(af[m0], bfr[nt], acc[m0][nt]);
    }
  }

  // stats: sum over the 16 l16 lanes (rows live per-quad)
  int sb = ((b*128 + r) << 7);
  #pragma unroll
  for (int mt = 0; mt < 2; ++mt)
    #pragma unroll
    for (int rg = 0; rg < 4; ++rg) {
      float s2 = sm[mt][rg];
      #pragma unroll
      for (int d2 = 1; d2 < 16; d2 <<= 1) s2 += __shfl_xor(s2, d2, 64);
      if (l16 == 0)
        so[sb + w*32 + mt*16 + quad*4 + rg] = s2;
    }

  // out-stage in own-wave ps block (wave-private; no barrier needed)
  __bf16* oS = (__bf16*)(smem + 21504 + 4608*w);   // [64][34] bf16
  #pragma unroll
  for (int m0 = 0; m0 < 4; ++m0)
    #pragma unroll
    for (int nt = 0; nt < 2; ++nt)
      #pragma unroll
      for (int rg = 0; rg < 4; ++rg)
        oS[(m0*16 + quad*4 + rg)*34 + nt*16 + l16] = (__bf16)acc[m0][nt][rg];
  ushort* dp = (ushort*)(dst + (size_t)b*1048576 + (size_t)r*128 + w*32);
  ushort* oSu = (ushort*)oS;
  for (int i = lane; i < 1024; i += 64) {
    int d = i >> 4, pp = (i & 15)*2;
    *(ushort2*)&dp[(size_t)d*16384 + pp] = *(ushort2*)&oSu[d*34 + pp];
  }
}

// Fused scale+combine:  Bo = gamma*(Bo + oT^T)/(sW+sH) + A.  Optionally
// writes Bo^T into BoT (may alias oT; tile staged to LDS first).
__global__ __launch_bounds__(256) void combineT_kernel(
    __bf16* __restrict__ Bo, const __bf16* oT,
    const __bf16* __restrict__ A,
    const float* __restrict__ sW, const float* __restrict__ sH,
    const float* __restrict__ gamma, __bf16* BoT, int writeT) {
  __shared__ float tile[32][33], ts[32][33];
  __shared__ float rt[32][33];
  int n = blockIdx.z;                       // b*64 + d
  int b = n >> 6;
  int x0 = blockIdx.x*32, y0 = blockIdx.y*32;
  const __bf16* ip = oT + (size_t)n*16384;
  const float* shp = sH + b*16384;
  for (int i = threadIdx.y; i < 32; i += 8) {
    tile[i][threadIdx.x] = (float)ip[(size_t)(y0 + i)*128 + x0 + threadIdx.x];
    ts[i][threadIdx.x] = shp[(y0 + i)*128 + x0 + threadIdx.x];
  }
  __syncthreads();
  float g = *gamma;
  for (int i = threadIdx.y; i < 32; i += 8) {
    int h = x0 + i, w2 = y0 + threadIdx.x;
    size_t idx = (size_t)n*16384 + (size_t)h*128 + w2;
    int pix = b*16384 + h*128 + w2;
    float inv = 1.0f / (sW[pix] + ts[threadIdx.x][i]);
    float res = g*((float)Bo[idx] + tile[threadIdx.x][i])*inv + (float)A[idx];
    Bo[idx] = (__bf16)res;
    rt[i][threadIdx.x] = res;               // (h=x0+i, w=y0+tx)
  }
  if (writeT) {
    __syncthreads();
    for (int i = threadIdx.y; i < 32; i += 8)
      BoT[(size_t)n*16384 + (size_t)(y0 + i)*128 + x0 + threadIdx.x] =
          (__bf16)rt[threadIdx.x][i];
  }
}

// MFMA pointwise 64->64 per (b,r) slice: out[o][p] = sum_c wpw[o][c]*A[c][p].
__global__ __launch_bounds__(256) void pw_kernel(
    const __bf16* __restrict__ A, const __bf16* __restrict__ ptab,
    float* __restrict__ out) {
  __shared__ __align__(16) char smem[33792];
  __bf16* ys = (__bf16*)smem;               // [128][72]
  int t = threadIdx.x;
  int r = blockIdx.x, b = blockIdx.y;
  const ushort* sp = (const ushort*)(A + (size_t)b*1048576 + (size_t)r*128);
  for (int i = t; i < 4096; i += 256) {
    int p = i & 127, c = (i >> 7)*2;
    ushort2 uv;
    uv.x = sp[(size_t)c*16384 + p];
    uv.y = sp[(size_t)(c + 1)*16384 + p];
    *(ushort2*)((ushort*)ys + p*72 + c) = uv;
  }
  int lane = t & 63, w = t >> 6;
  int l16 = lane & 15, quad = lane >> 4;
  bf8 a_w[4][2];
  #pragma unroll
  for (int m0 = 0; m0 < 4; ++m0)
    #pragma unroll
    for (int s = 0; s < 2; ++s)
      a_w[m0][s] = *(const bf8*)&ptab[((m0*2 + s)*64 + lane)*8];
  __syncthreads();                     // ys staged
  bf8 b_ys[2][2];
  #pragma unroll
  for (int nt = 0; nt < 2; ++nt) {
    int p = w*32 + nt*16 + l16;
    #pragma unroll
    for (int s = 0; s < 2; ++s)
      b_ys[nt][s] = *(const bf8*)&ys[p*72 + s*32 + quad*8];
  }
  __syncthreads();                     // all frag loads done; ys dead
  f4 z4 = {0.f, 0.f, 0.f, 0.f};
  f4 acc[4][2];
  #pragma unroll
  for (int m0 = 0; m0 < 4; ++m0)
    #pragma unroll
    for (int nt = 0; nt < 2; ++nt) {
      f4 a2 = z4;
      a2 = MFMA(a_w[m0][0], b_ys[nt][0], a2);
      a2 = MFMA(a_w[m0][1], b_ys[nt][1], a2);
      acc[m0][nt] = a2;
    }
  float* oS = (float*)(smem + 8448*w);  // [64][33] fp32, wave-local
  #pragma unroll
  for (int m0 = 0; m0 < 4; ++m0)
    #pragma unroll
    for (int nt = 0; nt < 2; ++nt)
      #pragma unroll
      for (int rg = 0; rg < 4; ++rg)
        oS[(m0*16 + quad*4 + rg)*33 + nt*16 + l16] = acc[m0][nt][rg];
  float* dp = out + (size_t)b*1048576 + (size_t)r*128 + w*32;
  for (int i = lane; i < 2048; i += 64) {
    int d = i >> 5, pp = i & 31;
    dp[(size_t)d*16384 + pp] = oS[d*33 + pp];
  }
}

extern "C" void kernel_launch(void* const* d_in, const int* in_sizes, int n_in,
                              void* d_out, int out_size, void* d_ws, size_t ws_size,
                              hipStream_t stream) {
  const float* x     = (const float*)d_in[0];
  const float* wdw   = (const float*)d_in[1];
  const float* wq    = (const float*)d_in[2];
  const float* wk    = (const float*)d_in[3];
  const float* wv    = (const float*)d_in[4];
  const float* gamma = (const float*)d_in[5];
  const float* wpw   = (const float*)d_in[6];
  float* out = (float*)d_out;

  // Workspace: y,z,AT bf16 (16 MB each) + wtab/ptab + 2 fp32 stat planes.
  __bf16* y    = (__bf16*)d_ws;
  __bf16* z    = y + 8388608;
  __bf16* AT   = z + 8388608;
  __bf16* wtab = AT + 8388608;        // 10 frags x 64 lanes x 8 = 5120
  __bf16* ptab = wtab + 5120;         // 8 frags x 64 lanes x 8 = 4096
  float* sW = (float*)(ptab + 4096);
  float* sH = sW + 131072;
  size_t need = (size_t)3*8388608*2 + (5120 + 4096)*2 + (size_t)2*131072*4;
  if (ws_size < need) return;

  prep_weights<<<1, 64, 0, stream>>>(wq, wk, wv, wpw, wtab, ptab);
  dwconv_kernel<<<dim3(4, 4, 512), 256, 0, stream>>>(x, wdw, y, AT);

  for (int pass = 0; pass < 2; ++pass) {
    const __bf16* A = pass ? z : y;   // CCA input / residual
    __bf16* Bo      = pass ? y : z;   // CCA output

    ccdir_kernel<<<dim3(128, 8, 2), 256, 0, stream>>>(
        A, Bo, AT, wtab, sW, sH);
    // pass 0: also write Bo^T into AT (next pass's transposed input)
    combineT_kernel<<<dim3(4, 4, 512), dim3(32, 8), 0, stream>>>(
        Bo, AT, A, sW, sH, gamma, AT, pass == 0 ? 1 : 0);
  }

  pw_kernel<<<dim3(128, 8), 256, 0, stream>>>(y, ptab, out);
}